// Round 17
// baseline (534.233 us; speedup 1.0000x reference)
//
#include <hip/hip_runtime.h>
#include <hip/hip_fp16.h>

// Problem constants (reference: B=16, T=2048, D=768)
#define DD 768
#define BB 16
#define TT 2048
#define BT (BB*TT)   // 32768
#define NQS 8        // 256-row blocks per batch for column-softmax stats
#define BST 76       // bounce tile stride (f16)

using f16 = _Float16;
typedef __attribute__((ext_vector_type(8)))  f16 half8;    // MFMA A/B frag (4 VGPR)
typedef __attribute__((ext_vector_type(4)))  f16 half4;
typedef __attribute__((ext_vector_type(16))) float f32x16; // 32x32 MFMA C/D frag

// XOR involution on 16B slots within a row: spreads K-slots across banks.
// Invariant under row+32k (bits 0-1 and (row>>2)&3 unchanged mod 32-row frags).
#define GSWZ(r) ((((r) & 3)) ^ (((r) >> 2) & 3))

typedef const __attribute__((address_space(1))) unsigned int* gas1;
typedef __attribute__((address_space(3))) unsigned int* las3;
__device__ __forceinline__ void gload16(const void* g, void* l){
  __builtin_amdgcn_global_load_lds((gas1)g, (las3)l, 16, 0, 0);
}

// ---------------- fp32 -> fp16 (x, full batch) ----------------
__global__ __launch_bounds__(256)
void tofp16_kernel(const float* __restrict__ src, f16* __restrict__ dst, int n4){
  const int stride = gridDim.x * 256;
  for (int i = blockIdx.x*256 + threadIdx.x; i < n4; i += stride){
    float4 v = ((const float4*)src)[i];
    half4 h; h[0]=(f16)v.x; h[1]=(f16)v.y; h[2]=(f16)v.z; h[3]=(f16)v.w;
    ((half4*)dst)[i] = h;
  }
}

// ---------------- weights fp32 -> f16, 3 planes in one dispatch ----------------
__global__ __launch_bounds__(256)
void wconv_kernel(const float* __restrict__ w0, const float* __restrict__ w1,
                  const float* __restrict__ w2, f16* __restrict__ dst){
  const float* src = blockIdx.y == 0 ? w0 : blockIdx.y == 1 ? w1 : w2;
  f16* d = dst + (size_t)blockIdx.y * DD * DD;
  const int n4 = DD*DD/4;
  const int stride = gridDim.x * 256;
  for (int i = blockIdx.x*256 + threadIdx.x; i < n4; i += stride){
    float4 v = ((const float4*)src)[i];
    half4 h; h[0]=(f16)v.x; h[1]=(f16)v.y; h[2]=(f16)v.z; h[3]=(f16)v.w;
    ((half4*)d)[i] = h;
  }
}

// =================================================================
// NT GEMM engine on 32x32x16 MFMA, 256 threads (4 waves 2Mx2N),
// BK=32, 3-deep LDS pipeline, counted vmcnt, XCD swizzle, LDS-bounce
// vectorized epilogue.
//   OMODE 0 (QKV proj)  : 256x128 block (FI=4), N-STACKED weights
//                         (ny=18, plane=by/6; plane 2 -> Vt transposed)
//   OMODE 1 (S -> P'')  : 256x128 block (FI=4), fused column stats
//   OMODE 2 (PV)        : 128x128 block (FI=2), A scaled by cs, 3/CU
// A/B frag: row = lane&31, k = (lane>>5)*8 + j (per 32-row fragment).
// C/D frag [HW-verified]: col = lane&31, row = (reg&3)+8*(reg>>2)+4*(lane>>5).
// =================================================================
template<int OMODE>
__global__ __launch_bounds__(256, OMODE==2 ? 3 : 2)
void gemmk(const f16* __restrict__ A, int lda, long sA,
           const f16* __restrict__ B, int ldb, long sB,
           void* __restrict__ Out, int ldc, long sC,
           const float* __restrict__ aux, int Kdim,
           float* __restrict__ f0, float* __restrict__ f1,
           const f16* __restrict__ cs, f16* __restrict__ vt)
{
  constexpr int FI = (OMODE==2) ? 2 : 4;   // 32-row frags per wave
  constexpr int BM = FI * 64;              // block rows (128 or 256)
  constexpr int AC = BM / 64;              // A staging chunks per thread

  __shared__ f16 lA[3][BM*32];             // 24 or 48 KB
  __shared__ f16 lB[3][128*32];            // 24 KB
  __shared__ float smx[OMODE==1 ? 4 : 1][2][32], szx[OMODE==1 ? 4 : 1][2][32];
  __shared__ f16 lCC[OMODE==2 ? 2048 : 8]; // softmax-correction row (PV)

  // XCD swizzle (nwg % 8 == 0 on all our grids)
  const int nx = gridDim.x, ny = gridDim.y, nwg = nx * ny, cpx = nwg >> 3;
  int h = blockIdx.x + nx * blockIdx.y;
  h = (h & 7) * cpx + (h >> 3);
  const int bx = h / ny, by = h % ny;

  const int b = blockIdx.z;
  const f16* A_ = A + (size_t)b * sA;
  const f16* B_ = B + (size_t)b * sB;
  const int m0 = bx * BM, n0 = by * 128;   // OMODE 0: n0 is the STACKED col
  const int tid = threadIdx.x, lane = tid & 63, wave = tid >> 6;
  const int wm = wave >> 1, wn = wave & 1;

  // staging: chunk c -> row=c>>2, dest slot c&3 (LDS linear),
  // SOURCE slot = (c&3) ^ GSWZ(row)  [involution]
  size_t gaO[AC], gbO[2];
#pragma unroll
  for (int k = 0; k < AC; ++k){
    int c = k*256 + tid, r = c >> 2, s = (c & 3) ^ GSWZ(r);
    gaO[k] = (size_t)(m0 + r) * lda + s * 8;
  }
#pragma unroll
  for (int k = 0; k < 2; ++k){
    int c = k*256 + tid, r = c >> 2, s = (c & 3) ^ GSWZ(r);
    gbO[k] = (size_t)(n0 + r) * ldb + s * 8;
  }

  f32x16 acc2[FI][2] = {};
  const int NT = Kdim >> 5;

  auto STAGE = [&](int u, int kt){
#pragma unroll
    for (int k = 0; k < AC; ++k) gload16(A_ + gaO[k] + kt, &lA[u][(k*256+tid)*8]);
#pragma unroll
    for (int k = 0; k < 2; ++k)  gload16(B_ + gbO[k] + kt, &lB[u][(k*256+tid)*8]);
  };

  if constexpr (OMODE == 2){
    const f16* cb = cs + ((size_t)b * NQS + (bx >> 1)) * TT;
    ((half8*)lCC)[tid] = ((const half8*)cb)[tid];
    __syncthreads();
  }

  STAGE(0, 0); STAGE(1, 32);   // 2 tiles ahead in flight

  const int row31 = lane & 31, khalf = lane >> 5;
  const int g = GSWZ(row31);
  const int slA = (wm*(FI*32) + row31)*32;
  const int slB = (wn*64 + row31)*32;
  const int s0 = ((khalf)     ^ g) * 8;    // ksub 0 swizzled slot (f16 units)
  const int s1 = ((2 + khalf) ^ g) * 8;    // ksub 1

  int u = 0;
  for (int t = 0; t < NT; ++t){
    int u2 = u + 2; if (u2 >= 3) u2 -= 3;
    __builtin_amdgcn_s_barrier();            // readers of buf[u2] (iter t-1) done
    __builtin_amdgcn_sched_barrier(0);
    if (t + 2 < NT) STAGE(u2, (t + 2) * 32);
    const int rem = NT - 1 - t;
    if constexpr (AC == 4){   // 6 loads/tile
      if (rem >= 2)      asm volatile("s_waitcnt vmcnt(12)" ::: "memory");
      else if (rem == 1) asm volatile("s_waitcnt vmcnt(6)"  ::: "memory");
      else               asm volatile("s_waitcnt vmcnt(0)"  ::: "memory");
    } else {                  // 4 loads/tile
      if (rem >= 2)      asm volatile("s_waitcnt vmcnt(8)" ::: "memory");
      else if (rem == 1) asm volatile("s_waitcnt vmcnt(4)" ::: "memory");
      else               asm volatile("s_waitcnt vmcnt(0)" ::: "memory");
    }
    __builtin_amdgcn_s_barrier();            // tile-t landed for all waves
    __builtin_amdgcn_sched_barrier(0);

    const f16* LA = &lA[u][0];
    const f16* LB = &lB[u][0];
    half8 aF[FI][2], bF[2][2];
#pragma unroll
    for (int fi = 0; fi < FI; ++fi){
      aF[fi][0] = *(const half8*)(LA + slA + fi*1024 + s0);
      aF[fi][1] = *(const half8*)(LA + slA + fi*1024 + s1);
    }
#pragma unroll
    for (int fj = 0; fj < 2; ++fj){
      bF[fj][0] = *(const half8*)(LB + slB + fj*1024 + s0);
      bF[fj][1] = *(const half8*)(LB + slB + fj*1024 + s1);
    }
    if constexpr (OMODE == 2){
      half8 cc0 = *(const half8*)&lCC[t*32 + khalf*8];
      half8 cc1 = *(const half8*)&lCC[t*32 + 16 + khalf*8];
#pragma unroll
      for (int fi = 0; fi < FI; ++fi){ aF[fi][0] *= cc0; aF[fi][1] *= cc1; }
    }
    __builtin_amdgcn_s_setprio(1);
#pragma unroll
    for (int fi = 0; fi < FI; ++fi)
#pragma unroll
      for (int fj = 0; fj < 2; ++fj){
        acc2[fi][fj] = __builtin_amdgcn_mfma_f32_32x32x16_f16(aF[fi][0], bF[fj][0], acc2[fi][fj], 0,0,0);
        acc2[fi][fj] = __builtin_amdgcn_mfma_f32_32x32x16_f16(aF[fi][1], bF[fj][1], acc2[fi][fj], 0,0,0);
      }
    __builtin_amdgcn_s_setprio(0);
    u = (u + 1 == 3) ? 0 : u + 1;
  }

  // ============ epilogue: LDS-bounce vectorized stores ============
  __syncthreads();   // all waves done reading pipeline LDS; safe to reuse
  f16* bnc = &lA[0][0] + wave * (16*BST);
  const int rr = lane >> 2, sB4 = lane & 3;   // read-phase: row, 16B slot

  if constexpr (OMODE == 0 || OMODE == 2){
    const int plane = (OMODE == 0) ? (by / 6) : 0;
    const int nloc0 = (OMODE == 0) ? (n0 - plane * DD) : n0;
    const bool toVt = (OMODE == 0) && (plane == 2);
    float bias2[2] = {};
    if constexpr (OMODE == 0){
#pragma unroll
      for (int fj = 0; fj < 2; ++fj) bias2[fj] = aux[n0 + wn*64 + fj*32 + row31];
    }
    f16* O = (f16*)Out + (OMODE == 0 ? (size_t)plane * sC : (size_t)b * sC);
#pragma unroll
    for (int fi = 0; fi < FI; ++fi)
#pragma unroll
      for (int oct = 0; oct < 2; ++oct){
#pragma unroll
        for (int fj = 0; fj < 2; ++fj)
#pragma unroll
          for (int r8 = 0; r8 < 8; ++r8){
            const int reg = oct*8 + r8;
            const int rl = (r8&3) + 8*(r8>>2) + 4*khalf;   // 0..15
            bnc[rl*BST + fj*32 + row31] = (f16)(acc2[fi][fj][reg] + bias2[fj]);
          }
        if (!toVt){
#pragma unroll
          for (int it = 0; it < 2; ++it){
            const int sIdx = sB4 + 4*it;                   // 0..7 (8 f16 each)
            half8 w = *(const half8*)&bnc[rr*BST + sIdx*8];
            const int gr = m0 + wm*(FI*32) + fi*32 + oct*16 + rr;
            const int gc = nloc0 + wn*64 + sIdx*8;
            *(half8*)&O[(size_t)gr*ldc + gc] = w;
          }
        } else {
          // V projection -> Vt[batch][v][token], 32B token strips
          f16 tmp[16];
#pragma unroll
          for (int k = 0; k < 16; ++k) tmp[k] = bnc[k*BST + lane];
          half8 v0, v1;
#pragma unroll
          for (int k = 0; k < 8; ++k){ v0[k] = tmp[k]; v1[k] = tmp[8+k]; }
          const int tokg = m0 + wm*(FI*32) + fi*32 + oct*16;
          const int batch = tokg >> 11, tok = tokg & (TT-1);
          f16* Vo = vt + ((size_t)batch*DD + nloc0 + wn*64 + lane)*TT + tok;
          *(half8*)&Vo[0] = v0;
          *(half8*)&Vo[8] = v1;
        }
      }
  } else {
    // S -> P'' = exp(S - M_blk) f16, + per-(256-rowblock,column) partials
    f16* O = (f16*)Out + (size_t)b * sC;
    float Mb2[2];
#pragma unroll
    for (int fj = 0; fj < 2; ++fj){
      float mx = acc2[0][fj][0];
#pragma unroll
      for (int fi = 0; fi < FI; ++fi)
#pragma unroll
        for (int reg = 0; reg < 16; ++reg) mx = fmaxf(mx, acc2[fi][fj][reg]);
      mx = fmaxf(mx, __shfl_xor(mx, 32, 64));
      if (lane < 32) smx[wave][fj][lane] = mx;
      Mb2[fj] = mx;
    }
    __syncthreads();
#pragma unroll
    for (int fj = 0; fj < 2; ++fj)
      Mb2[fj] = fmaxf(Mb2[fj], smx[wave ^ 2][fj][row31]);   // block column max
    float zz2[2] = {0.f, 0.f};
#pragma unroll
    for (int fi = 0; fi < FI; ++fi)
#pragma unroll
      for (int oct = 0; oct < 2; ++oct){
#pragma unroll
        for (int fj = 0; fj < 2; ++fj)
#pragma unroll
          for (int r8 = 0; r8 < 8; ++r8){
            const int reg = oct*8 + r8;
            const int rl = (r8&3) + 8*(r8>>2) + 4*khalf;
            float e = __expf(acc2[fi][fj][reg] - Mb2[fj]);
            zz2[fj] += e;
            bnc[rl*BST + fj*32 + row31] = (f16)e;
          }
#pragma unroll
        for (int it = 0; it < 2; ++it){
          const int sIdx = sB4 + 4*it;
          half8 w = *(const half8*)&bnc[rr*BST + sIdx*8];
          const int gr = m0 + wm*(FI*32) + fi*32 + oct*16 + rr;
          const int gc = n0 + wn*64 + sIdx*8;
          *(half8*)&O[(size_t)gr*ldc + gc] = w;
        }
      }
#pragma unroll
    for (int fj = 0; fj < 2; ++fj){
      zz2[fj] += __shfl_xor(zz2[fj], 32, 64);
      if (lane < 32) szx[wave][fj][lane] = zz2[fj];
    }
    __syncthreads();
    if (wm == 0 && lane < 32){
#pragma unroll
      for (int fj = 0; fj < 2; ++fj){
        const int gc = n0 + wn*64 + fj*32 + lane;
        size_t o = ((size_t)b * NQS + bx) * TT + gc;
        f0[o] = Mb2[fj];
        f1[o] = zz2[fj] + szx[wave + 2][fj][lane];
      }
    }
  }
}

// ------- merge NQS partials; emit c[rb][t] = exp(pm - M) * zinv as f16 -------
__global__ __launch_bounds__(256)
void statsB_kernel(const float* __restrict__ pm, const float* __restrict__ pz,
                   f16* __restrict__ c){
  const int b = blockIdx.y;
  const int t = blockIdx.x * 256 + threadIdx.x;
  float am[NQS], az[NQS];
#pragma unroll
  for (int k = 0; k < NQS; ++k){
    size_t o = ((size_t)b * NQS + k) * TT + t;
    am[k] = pm[o]; az[k] = pz[o];
  }
  float M = am[0];
#pragma unroll
  for (int k = 1; k < NQS; ++k) M = fmaxf(M, am[k]);
  float Z = 0.f;
#pragma unroll
  for (int k = 0; k < NQS; ++k) Z += az[k] * __expf(am[k] - M);
  const float zi = 1.f / (Z * 27.712812921102035f);  // 1/(Z*sqrt(768))
#pragma unroll
  for (int k = 0; k < NQS; ++k)
    c[((size_t)b * NQS + k) * TT + t] = (f16)(__expf(am[k] - M) * zi);
}

// ------- residual + LayerNorm: out = LN(applied_f16 + x_f16) -------
__global__ __launch_bounds__(192)
void ln2_kernel(const half4* __restrict__ applied, const half4* __restrict__ xf,
                const float4* __restrict__ gamma4, const float4* __restrict__ beta4,
                float4* __restrict__ out){
  const size_t base = (size_t)blockIdx.x * (DD/4);
  const int cc = threadIdx.x;          // 0..191
  half4 a4 = applied[base + cc];
  half4 x4 = xf[base + cc];
  float y0 = (float)a4[0] + (float)x4[0];
  float y1 = (float)a4[1] + (float)x4[1];
  float y2 = (float)a4[2] + (float)x4[2];
  float y3 = (float)a4[3] + (float)x4[3];
  float s = y0+y1+y2+y3;
  float sq = y0*y0+y1*y1+y2*y2+y3*y3;
#pragma unroll
  for (int off = 32; off > 0; off >>= 1){
    s  += __shfl_down(s,  off, 64);
    sq += __shfl_down(sq, off, 64);
  }
  __shared__ float rs_[3], rq_[3];
  const int lane = threadIdx.x & 63, w = threadIdx.x >> 6;
  if (lane == 0){ rs_[w] = s; rq_[w] = sq; }
  __syncthreads();
  const float S_ = rs_[0]+rs_[1]+rs_[2];
  const float Q_ = rq_[0]+rq_[1]+rq_[2];
  const float mu  = S_ * (1.f/DD);
  const float var = Q_ * (1.f/DD) - mu*mu;
  const float rstd = rsqrtf(var + 1e-5f);
  float4 g = gamma4[cc], be = beta4[cc], o;
  o.x = (y0 - mu)*rstd*g.x + be.x;
  o.y = (y1 - mu)*rstd*g.y + be.y;
  o.z = (y2 - mu)*rstd*g.z + be.z;
  o.w = (y3 - mu)*rstd*g.w + be.w;
  out[base + cc] = o;
}

extern "C" void kernel_launch(void* const* d_in, const int* in_sizes, int n_in,
                              void* d_out, int out_size, void* d_ws, size_t ws_size,
                              hipStream_t stream)
{
  const float* x    = (const float*)d_in[0];
  const float* Wk   = (const float*)d_in[1];
  const float* bk   = (const float*)d_in[2];
  const float* Wq   = (const float*)d_in[3];
  const float* bq   = (const float*)d_in[4];
  const float* Wv   = (const float*)d_in[5];
  const float* bv   = (const float*)d_in[6];
  const float* gamma= (const float*)d_in[7];
  const float* beta = (const float*)d_in[8];
  float* out = (float*)d_out;

  const size_t PW = (size_t)DD*DD*2;    // f16 weight plane
  const size_t PB = (size_t)TT*DD*2;    // f16 activation plane per batch
  const size_t T4 = (size_t)TT*4;
  auto al = [](size_t n){ return (n + 255) & ~(size_t)255; };

  auto need = [&](int G)->size_t{
    size_t t = al(3*PW) + al(3*DD*4) + al((size_t)BB*PB) + al((size_t)BB*TT*TT*2)
             + al((size_t)BB*PB) + al(2*(size_t)G*PB)
             + 2*al((size_t)G*NQS*T4) + al((size_t)BB*NQS*TT*2);
    if (2*(size_t)G*PB < (size_t)BB*PB) t += al((size_t)BB*PB);
    return t;
  };

  int G = 0;
  for (int g : {16, 8, 4, 2, 1}) if (need(g) <= ws_size){ G = g; break; }
  if (G == 0) return;

  char* p = (char*)d_ws;
  auto alloc = [&](size_t n)->char*{ char* r = p; p += (n + 255) & ~(size_t)255; return r; };
  f16*   Wf    = (f16*)alloc(3*PW);            // [Wq;Wk;Wv] N-stacked [2304][768]
  float* biasf = (float*)alloc(3*DD*4);        // [bq;bk;bv] stacked [2304]
  f16*   Vt    = (f16*)alloc((size_t)BB*PB);
  f16*   P16   = (f16*)alloc((size_t)BB*TT*TT*2);
  f16*   Xf    = (f16*)alloc((size_t)BB*PB);   // full-batch x f16 (alive to ln2)
  f16*   QKVc  = (f16*)alloc(2*(size_t)G*PB);  // Q,K chunk planes (V -> Vt direct)
  float* pm    = (float*)alloc((size_t)G*NQS*T4);
  float* pz    = (float*)alloc((size_t)G*NQS*T4);
  f16*   cbuf  = (f16*)alloc((size_t)BB*NQS*TT*2);
  f16* applied = (2*(size_t)G*PB >= (size_t)BB*PB) ? QKVc
               : (f16*)alloc((size_t)BB*PB);
  f16* Qc = QKVc, *Kc = QKVc + (size_t)G*TT*DD;

  wconv_kernel<<<dim3(288, 3), 256, 0, stream>>>(Wq, Wk, Wv, Wf);
  hipMemcpyAsync(biasf,        bq, DD*4, hipMemcpyDeviceToDevice, stream);
  hipMemcpyAsync(biasf +   DD, bk, DD*4, hipMemcpyDeviceToDevice, stream);
  hipMemcpyAsync(biasf + 2*DD, bv, DD*4, hipMemcpyDeviceToDevice, stream);
  tofp16_kernel<<<2048, 256, 0, stream>>>(x, Xf, BT*DD/4);

  const int nRows = G * TT;
  for (int b0 = 0; b0 < BB; b0 += G){
    // N-stacked Q|K|V projection: ny=18 (plane = by/6); V -> Vt transposed
    dim3 gp(nRows/256, 3*DD/128, 1);
    gemmk<0><<<gp, 256, 0, stream>>>(Xf + (size_t)b0*TT*DD, DD, 0,
                                     Wf, DD, 0,
                                     QKVc, DD, (long)G*TT*DD, biasf, DD,
                                     nullptr, nullptr, nullptr,
                                     Vt + (size_t)b0*DD*TT);

    // S = Q K^T -> P'' f16 into P16, + stats partials
    dim3 gs(TT/256, TT/128, G);
    gemmk<1><<<gs, 256, 0, stream>>>(Qc, DD, (long)TT*DD, Kc, DD, (long)TT*DD,
                                     P16 + (size_t)b0*TT*TT, TT, (long)TT*TT,
                                     nullptr, DD, pm, pz, nullptr, nullptr);

    statsB_kernel<<<dim3(TT/256, G), 256, 0, stream>>>(
        pm, pz, cbuf + (size_t)b0*NQS*TT);
  }

  // PV over all batches -> applied f16 (correction folded into A-frags)
  dim3 gpv(TT/128, DD/128, BB);
  gemmk<2><<<gpv, 256, 0, stream>>>(P16, TT, (long)TT*TT, Vt, TT, (long)DD*TT,
                                    applied, DD, (long)TT*DD, nullptr, TT,
                                    nullptr, nullptr, cbuf, nullptr);

  ln2_kernel<<<BT, 192, 0, stream>>>((const half4*)applied, (const half4*)Xf,
                                     (const float4*)gamma, (const float4*)beta,
                                     (float4*)out);
}

// Round 18
// 514.809 us; speedup vs baseline: 1.0377x; 1.0377x over previous
//
#include <hip/hip_runtime.h>
#include <hip/hip_fp16.h>

// Problem constants (reference: B=16, T=2048, D=768)
#define DD 768
#define BB 16
#define TT 2048
#define BT (BB*TT)   // 32768
#define NQS 8        // 256-row blocks per batch for column-softmax stats
#define BST 76       // bounce tile stride (f16): conflict-free write+read phases

using f16 = _Float16;
typedef __attribute__((ext_vector_type(8))) f16 half8;   // MFMA A/B frag (4 VGPR)
typedef __attribute__((ext_vector_type(4))) f16 half4;   // 8B
typedef __attribute__((ext_vector_type(4))) float f32x4; // MFMA C/D frag

// XOR involution on 16B slots within a row: spreads K-slots across banks
#define GSWZ(r) ((((r) & 3)) ^ (((r) >> 2) & 3))

typedef const __attribute__((address_space(1))) unsigned int* gas1;
typedef __attribute__((address_space(3))) unsigned int* las3;
__device__ __forceinline__ void gload16(const void* g, void* l){
  __builtin_amdgcn_global_load_lds((gas1)g, (las3)l, 16, 0, 0);
}

// ---------------- fp32 -> fp16 (x, full batch) ----------------
__global__ __launch_bounds__(256)
void tofp16_kernel(const float* __restrict__ src, f16* __restrict__ dst, int n4){
  const int stride = gridDim.x * 256;
  for (int i = blockIdx.x*256 + threadIdx.x; i < n4; i += stride){
    float4 v = ((const float4*)src)[i];
    half4 h; h[0]=(f16)v.x; h[1]=(f16)v.y; h[2]=(f16)v.z; h[3]=(f16)v.w;
    ((half4*)dst)[i] = h;
  }
}

// ---------------- weights fp32 -> f16, 3 planes in one dispatch ----------------
__global__ __launch_bounds__(256)
void wconv_kernel(const float* __restrict__ w0, const float* __restrict__ w1,
                  const float* __restrict__ w2, f16* __restrict__ dst){
  const float* src = blockIdx.y == 0 ? w0 : blockIdx.y == 1 ? w1 : w2;
  f16* d = dst + (size_t)blockIdx.y * DD * DD;
  const int n4 = DD*DD/4;
  const int stride = gridDim.x * 256;
  for (int i = blockIdx.x*256 + threadIdx.x; i < n4; i += stride){
    float4 v = ((const float4*)src)[i];
    half4 h; h[0]=(f16)v.x; h[1]=(f16)v.y; h[2]=(f16)v.z; h[3]=(f16)v.w;
    ((half4*)d)[i] = h;
  }
}

// =================================================================
// NT GEMM engine (best measured config, r16), 256 threads (4 waves
// 2Mx2N), BK=32, 3-deep LDS pipeline, counted vmcnt, XCD swizzle
// (A-panel reuse), LDS-bounce vectorized epilogue, 16x16x32 MFMA.
//   OMODE 0 (QKV proj)  : 256x128 block, N-STACKED weights (ny=18,
//                         plane = by/6; plane 2 writes Vt transposed)
//   OMODE 1 (S -> P'')  : 256x128 block, 8x4 acc/wave, 2 blocks/CU
//   OMODE 2 (PV)        : 128x128 block, 4x4 acc/wave, 3 blocks/CU
// =================================================================
template<int OMODE>
__global__ __launch_bounds__(256, OMODE==2 ? 3 : 2)
void gemmk(const f16* __restrict__ A, int lda, long sA,
           const f16* __restrict__ B, int ldb, long sB,
           void* __restrict__ Out, int ldc, long sC,
           const float* __restrict__ aux, int Kdim,
           float* __restrict__ f0, float* __restrict__ f1,
           const f16* __restrict__ cs, f16* __restrict__ vt)
{
  constexpr int MR = (OMODE==2) ? 4 : 8;   // m-frag reps per wave
  constexpr int BM = MR * 32;              // block rows (128 or 256)
  constexpr int AC = BM / 64;              // A staging chunks per thread

  __shared__ f16 lA[3][BM*32];             // 24 or 48 KB
  __shared__ f16 lB[3][128*32];            // 24 KB
  __shared__ float smx[OMODE==1 ? 4 : 1][4][16], szx[OMODE==1 ? 4 : 1][4][16];
  __shared__ f16 lCC[OMODE==2 ? 2048 : 8]; // softmax-correction row (PV)

  // XCD swizzle (nwg % 8 == 0 on all our grids): XCD k owns a contiguous
  // work range decoded by-FASTEST so consecutive works share the A-panel.
  const int nx = gridDim.x, ny = gridDim.y, nwg = nx * ny, cpx = nwg >> 3;
  int h = blockIdx.x + nx * blockIdx.y;
  h = (h & 7) * cpx + (h >> 3);
  const int bx = h / ny, by = h % ny;

  const int b = blockIdx.z;
  const f16* A_ = A + (size_t)b * sA;
  const f16* B_ = B + (size_t)b * sB;
  const int m0 = bx * BM, n0 = by * 128;   // OMODE 0: n0 is the STACKED col
  const int tid = threadIdx.x, lane = tid & 63, wave = tid >> 6;
  const int wm = wave >> 1, wn = wave & 1;

  // staging: chunk c -> row=c>>2, dest slot c&3 (LDS linear),
  // SOURCE slot = (c&3) ^ GSWZ(row)  [involution]
  size_t gaO[AC], gbO[2];
#pragma unroll
  for (int k = 0; k < AC; ++k){
    int c = k*256 + tid, r = c >> 2, s = (c & 3) ^ GSWZ(r);
    gaO[k] = (size_t)(m0 + r) * lda + s * 8;
  }
#pragma unroll
  for (int k = 0; k < 2; ++k){
    int c = k*256 + tid, r = c >> 2, s = (c & 3) ^ GSWZ(r);
    gbO[k] = (size_t)(n0 + r) * ldb + s * 8;
  }

  f32x4 acc[MR][4] = {};
  const int NT = Kdim >> 5;

  auto STAGE = [&](int u, int kt){
#pragma unroll
    for (int k = 0; k < AC; ++k) gload16(A_ + gaO[k] + kt, &lA[u][(k*256+tid)*8]);
#pragma unroll
    for (int k = 0; k < 2; ++k)  gload16(B_ + gbO[k] + kt, &lB[u][(k*256+tid)*8]);
  };

  if constexpr (OMODE == 2){
    // preload softmax-correction row: stats rb = bx>>1 (256-row stats blocks)
    const f16* cb = cs + ((size_t)b * NQS + (bx >> 1)) * TT;
    ((half8*)lCC)[tid] = ((const half8*)cb)[tid];
    __syncthreads();
  }

  STAGE(0, 0); STAGE(1, 32);   // 2 tiles ahead in flight

  const int frow = lane & 15;
  const int rsl = (((lane >> 4) ^ GSWZ(frow)) & 3) * 8;   // swizzled LDS slot
  const int tsl = (lane >> 4) * 8;                        // logical K slot
  const int offA = (wm*(MR*16) + frow)*32 + rsl;
  const int offB = (wn*64 + frow)*32 + rsl;

  int u = 0;
  for (int t = 0; t < NT; ++t){
    int u2 = u + 2; if (u2 >= 3) u2 -= 3;
    __builtin_amdgcn_s_barrier();            // readers of buf[u2] (iter t-1) done
    __builtin_amdgcn_sched_barrier(0);
    if (t + 2 < NT) STAGE(u2, (t + 2) * 32);
    const int rem = NT - 1 - t;
    if constexpr (AC == 4){   // 6 loads/tile
      if (rem >= 2)      asm volatile("s_waitcnt vmcnt(12)" ::: "memory");
      else if (rem == 1) asm volatile("s_waitcnt vmcnt(6)"  ::: "memory");
      else               asm volatile("s_waitcnt vmcnt(0)"  ::: "memory");
    } else {                  // 4 loads/tile
      if (rem >= 2)      asm volatile("s_waitcnt vmcnt(8)" ::: "memory");
      else if (rem == 1) asm volatile("s_waitcnt vmcnt(4)" ::: "memory");
      else               asm volatile("s_waitcnt vmcnt(0)" ::: "memory");
    }
    __builtin_amdgcn_s_barrier();            // tile-t landed for all waves
    __builtin_amdgcn_sched_barrier(0);

    const f16* tA = &lA[u][0] + offA;
    const f16* tB = &lB[u][0] + offB;
    half8 af[MR], bf[4];
#pragma unroll
    for (int i = 0; i < MR; ++i) af[i] = *(const half8*)(tA + i*512);
#pragma unroll
    for (int j = 0; j < 4; ++j)  bf[j] = *(const half8*)(tB + j*512);
    if constexpr (OMODE == 2){
      half8 cc = *(const half8*)&lCC[t*32 + tsl];   // P = P'' * c, folded into A
#pragma unroll
      for (int i = 0; i < MR; ++i) af[i] *= cc;
    }
    __builtin_amdgcn_s_setprio(1);
#pragma unroll
    for (int i = 0; i < MR; ++i)
#pragma unroll
      for (int j = 0; j < 4; ++j)
        acc[i][j] = __builtin_amdgcn_mfma_f32_16x16x32_f16(af[i], bf[j], acc[i][j], 0,0,0);
    __builtin_amdgcn_s_setprio(0);
    u = (u + 1 == 3) ? 0 : u + 1;
  }

  // ============ epilogue: LDS-bounce vectorized stores ============
  // C/D layout: col = lane&15, row = (lane>>4)*4 + r  [m89 verified].
  __syncthreads();   // all waves done reading pipeline LDS; safe to reuse
  const int kq4 = (lane >> 4) * 4;
  f16* bnc = &lA[0][0] + wave * (16*BST);
  const int rrow = lane >> 2, rcol = (lane & 3) * 16;   // read-phase mapping

  if constexpr (OMODE == 0 || OMODE == 2){
    // OMODE 0: plane = by/6 (0=Q,1=K,2=V); nloc = within-plane column base
    const int plane = (OMODE == 0) ? (by / 6) : 0;
    const int nloc0 = (OMODE == 0) ? (n0 - plane * DD) : n0;
    const bool toVt = (OMODE == 0) && (plane == 2);
    float bias4[4] = {};
    if constexpr (OMODE == 0){
#pragma unroll
      for (int j = 0; j < 4; ++j) bias4[j] = aux[n0 + wn*64 + j*16 + frow];
    }
    f16* O = (f16*)Out + (OMODE == 0 ? (size_t)plane * sC : (size_t)b * sC);
#pragma unroll
    for (int i = 0; i < MR; ++i){
#pragma unroll
      for (int j = 0; j < 4; ++j)
#pragma unroll
        for (int r = 0; r < 4; ++r)
          bnc[(kq4 + r)*BST + j*16 + frow] = (f16)(acc[i][j][r] + bias4[j]);
      if (!toVt){
        half8 w0 = *(const half8*)&bnc[rrow*BST + rcol];
        half8 w1 = *(const half8*)&bnc[rrow*BST + rcol + 8];
        const int gr = m0 + wm*(MR*16) + i*16 + rrow;
        const int gc = nloc0 + wn*64 + rcol;
        *(half8*)&O[(size_t)gr*ldc + gc]     = w0;
        *(half8*)&O[(size_t)gr*ldc + gc + 8] = w1;
      } else {
        // V projection -> Vt[batch][v][token], 32B-contiguous token strips
        f16 tmp[16];
#pragma unroll
        for (int k = 0; k < 16; ++k) tmp[k] = bnc[k*BST + lane];
        half8 v0, v1;
#pragma unroll
        for (int k = 0; k < 8; ++k){ v0[k] = tmp[k]; v1[k] = tmp[8+k]; }
        const int tokg = m0 + wm*(MR*16) + i*16;
        const int batch = tokg >> 11, tok = tokg & (TT-1);
        f16* Vo = vt + ((size_t)batch*DD + nloc0 + wn*64 + lane)*TT + tok;
        *(half8*)&Vo[0] = v0;
        *(half8*)&Vo[8] = v1;
      }
    }
  } else {
    // S -> P'' = exp(S - M_blk) f16, + per-(256-rowblock,column) partials
    f16* O = (f16*)Out + (size_t)b * sC;
    float Mb[4];
#pragma unroll
    for (int j = 0; j < 4; ++j){
      float mx = acc[0][j][0];
#pragma unroll
      for (int i = 0; i < MR; ++i)
#pragma unroll
        for (int r = 0; r < 4; ++r) mx = fmaxf(mx, acc[i][j][r]);
      mx = fmaxf(mx, __shfl_xor(mx, 16, 64));
      mx = fmaxf(mx, __shfl_xor(mx, 32, 64));
      if (lane < 16) smx[wave][j][lane] = mx;
      Mb[j] = mx;
    }
    __syncthreads();
#pragma unroll
    for (int j = 0; j < 4; ++j)
      Mb[j] = fmaxf(Mb[j], smx[wave ^ 2][j][frow]);   // block-level column max
    float zz[4] = {};
#pragma unroll
    for (int i = 0; i < MR; ++i){
#pragma unroll
      for (int j = 0; j < 4; ++j)
#pragma unroll
        for (int r = 0; r < 4; ++r){
          float e = __expf(acc[i][j][r] - Mb[j]);
          zz[j] += e;
          bnc[(kq4 + r)*BST + j*16 + frow] = (f16)e;
        }
      half8 w0 = *(const half8*)&bnc[rrow*BST + rcol];
      half8 w1 = *(const half8*)&bnc[rrow*BST + rcol + 8];
      const int gr = m0 + wm*(MR*16) + i*16 + rrow;
      const int gc = n0 + wn*64 + rcol;
      *(half8*)&O[(size_t)gr*ldc + gc]     = w0;
      *(half8*)&O[(size_t)gr*ldc + gc + 8] = w1;
    }
#pragma unroll
    for (int j = 0; j < 4; ++j){
      zz[j] += __shfl_xor(zz[j], 16, 64);
      zz[j] += __shfl_xor(zz[j], 32, 64);
      if (lane < 16) szx[wave][j][lane] = zz[j];
    }
    __syncthreads();
    if (wm == 0 && lane < 16){
#pragma unroll
      for (int j = 0; j < 4; ++j){
        const int gc = n0 + wn*64 + j*16 + lane;
        size_t o = ((size_t)b * NQS + bx) * TT + gc;
        f0[o] = Mb[j];
        f1[o] = zz[j] + szx[wave + 2][j][lane];
      }
    }
  }
}

// ------- merge NQS partials; emit c[rb][t] = exp(pm - M) * zinv as f16 -------
__global__ __launch_bounds__(256)
void statsB_kernel(const float* __restrict__ pm, const float* __restrict__ pz,
                   f16* __restrict__ c){
  const int b = blockIdx.y;
  const int t = blockIdx.x * 256 + threadIdx.x;
  float am[NQS], az[NQS];
#pragma unroll
  for (int k = 0; k < NQS; ++k){
    size_t o = ((size_t)b * NQS + k) * TT + t;
    am[k] = pm[o]; az[k] = pz[o];
  }
  float M = am[0];
#pragma unroll
  for (int k = 1; k < NQS; ++k) M = fmaxf(M, am[k]);
  float Z = 0.f;
#pragma unroll
  for (int k = 0; k < NQS; ++k) Z += az[k] * __expf(am[k] - M);
  const float zi = 1.f / (Z * 27.712812921102035f);  // 1/(Z*sqrt(768))
#pragma unroll
  for (int k = 0; k < NQS; ++k)
    c[((size_t)b * NQS + k) * TT + t] = (f16)(__expf(am[k] - M) * zi);
}

// ------- residual + LayerNorm: out = LN(applied_f16 + x_f16) -------
__global__ __launch_bounds__(192)
void ln2_kernel(const half4* __restrict__ applied, const half4* __restrict__ xf,
                const float4* __restrict__ gamma4, const float4* __restrict__ beta4,
                float4* __restrict__ out){
  const size_t base = (size_t)blockIdx.x * (DD/4);
  const int cc = threadIdx.x;          // 0..191
  half4 a4 = applied[base + cc];
  half4 x4 = xf[base + cc];
  float y0 = (float)a4[0] + (float)x4[0];
  float y1 = (float)a4[1] + (float)x4[1];
  float y2 = (float)a4[2] + (float)x4[2];
  float y3 = (float)a4[3] + (float)x4[3];
  float s = y0+y1+y2+y3;
  float sq = y0*y0+y1*y1+y2*y2+y3*y3;
#pragma unroll
  for (int off = 32; off > 0; off >>= 1){
    s  += __shfl_down(s,  off, 64);
    sq += __shfl_down(sq, off, 64);
  }
  __shared__ float rs_[3], rq_[3];
  const int lane = threadIdx.x & 63, w = threadIdx.x >> 6;
  if (lane == 0){ rs_[w] = s; rq_[w] = sq; }
  __syncthreads();
  const float S_ = rs_[0]+rs_[1]+rs_[2];
  const float Q_ = rq_[0]+rq_[1]+rq_[2];
  const float mu  = S_ * (1.f/DD);
  const float var = Q_ * (1.f/DD) - mu*mu;
  const float rstd = rsqrtf(var + 1e-5f);
  float4 g = gamma4[cc], be = beta4[cc], o;
  o.x = (y0 - mu)*rstd*g.x + be.x;
  o.y = (y1 - mu)*rstd*g.y + be.y;
  o.z = (y2 - mu)*rstd*g.z + be.z;
  o.w = (y3 - mu)*rstd*g.w + be.w;
  out[base + cc] = o;
}

extern "C" void kernel_launch(void* const* d_in, const int* in_sizes, int n_in,
                              void* d_out, int out_size, void* d_ws, size_t ws_size,
                              hipStream_t stream)
{
  const float* x    = (const float*)d_in[0];
  const float* Wk   = (const float*)d_in[1];
  const float* bk   = (const float*)d_in[2];
  const float* Wq   = (const float*)d_in[3];
  const float* bq   = (const float*)d_in[4];
  const float* Wv   = (const float*)d_in[5];
  const float* bv   = (const float*)d_in[6];
  const float* gamma= (const float*)d_in[7];
  const float* beta = (const float*)d_in[8];
  float* out = (float*)d_out;

  const size_t PW = (size_t)DD*DD*2;    // f16 weight plane
  const size_t PB = (size_t)TT*DD*2;    // f16 activation plane per batch
  const size_t T4 = (size_t)TT*4;
  auto al = [](size_t n){ return (n + 255) & ~(size_t)255; };

  auto need = [&](int G)->size_t{
    size_t t = al(3*PW) + al(3*DD*4) + al((size_t)BB*PB) + al((size_t)BB*TT*TT*2)
             + al((size_t)BB*PB) + al(2*(size_t)G*PB)
             + 2*al((size_t)G*NQS*T4) + al((size_t)BB*NQS*TT*2);
    if (2*(size_t)G*PB < (size_t)BB*PB) t += al((size_t)BB*PB);
    return t;
  };

  int G = 0;
  for (int g : {16, 8, 4, 2, 1}) if (need(g) <= ws_size){ G = g; break; }
  if (G == 0) return;

  char* p = (char*)d_ws;
  auto alloc = [&](size_t n)->char*{ char* r = p; p += (n + 255) & ~(size_t)255; return r; };
  f16*   Wf    = (f16*)alloc(3*PW);            // [Wq;Wk;Wv] N-stacked [2304][768]
  float* biasf = (float*)alloc(3*DD*4);        // [bq;bk;bv] stacked [2304]
  f16*   Vt    = (f16*)alloc((size_t)BB*PB);
  f16*   P16   = (f16*)alloc((size_t)BB*TT*TT*2);
  f16*   Xf    = (f16*)alloc((size_t)BB*PB);   // full-batch x in f16 (alive to ln2)
  f16*   QKVc  = (f16*)alloc(2*(size_t)G*PB);  // Q,K chunk planes (V -> Vt direct)
  float* pm    = (float*)alloc((size_t)G*NQS*T4);
  float* pz    = (float*)alloc((size_t)G*NQS*T4);
  f16*   cbuf  = (f16*)alloc((size_t)BB*NQS*TT*2);
  f16* applied = (2*(size_t)G*PB >= (size_t)BB*PB) ? QKVc
               : (f16*)alloc((size_t)BB*PB);
  f16* Qc = QKVc, *Kc = QKVc + (size_t)G*TT*DD;

  wconv_kernel<<<dim3(288, 3), 256, 0, stream>>>(Wq, Wk, Wv, Wf);
  hipMemcpyAsync(biasf,        bq, DD*4, hipMemcpyDeviceToDevice, stream);
  hipMemcpyAsync(biasf +   DD, bk, DD*4, hipMemcpyDeviceToDevice, stream);
  hipMemcpyAsync(biasf + 2*DD, bv, DD*4, hipMemcpyDeviceToDevice, stream);
  tofp16_kernel<<<2048, 256, 0, stream>>>(x, Xf, BT*DD/4);

  const int nRows = G * TT;
  for (int b0 = 0; b0 < BB; b0 += G){
    // N-stacked Q|K|V projection: ny=18 (plane = by/6); V -> Vt transposed
    dim3 gp(nRows/256, 3*DD/128, 1);
    gemmk<0><<<gp, 256, 0, stream>>>(Xf + (size_t)b0*TT*DD, DD, 0,
                                     Wf, DD, 0,
                                     QKVc, DD, (long)G*TT*DD, biasf, DD,
                                     nullptr, nullptr, nullptr,
                                     Vt + (size_t)b0*DD*TT);

    // S = Q K^T -> P'' f16 directly into P16, + stats partials
    dim3 gs(TT/256, TT/128, G);
    gemmk<1><<<gs, 256, 0, stream>>>(Qc, DD, (long)TT*DD, Kc, DD, (long)TT*DD,
                                     P16 + (size_t)b0*TT*TT, TT, (long)TT*TT,
                                     nullptr, DD, pm, pz, nullptr, nullptr);

    statsB_kernel<<<dim3(TT/256, G), 256, 0, stream>>>(
        pm, pz, cbuf + (size_t)b0*NQS*TT);
  }

  // PV over all batches -> applied f16 (correction folded into A-frags)
  dim3 gpv(TT/128, DD/128, BB);
  gemmk<2><<<gpv, 256, 0, stream>>>(P16, TT, (long)TT*TT, Vt, TT, (long)DD*TT,
                                    applied, DD, (long)TT*DD, nullptr, TT,
                                    nullptr, nullptr, cbuf, nullptr);

  ln2_kernel<<<BT, 192, 0, stream>>>((const half4*)applied, (const half4*)Xf,
                                     (const float4*)gamma, (const float4*)beta,
                                     (float4*)out);
}